// Round 5
// baseline (1647.959 us; speedup 1.0000x reference)
//
#include <hip/hip_runtime.h>
#include <hip/hip_bf16.h>

#define T_TOK 8192
#define H_DIM 1024
#define I_DIM 4096
#define NEXP 8

typedef __bf16 bf16x8 __attribute__((ext_vector_type(8)));
typedef float f32x4 __attribute__((ext_vector_type(4)));
typedef unsigned short u16;

#define AS3(p) ((__attribute__((address_space(3))) void*)(p))
#define AS1(p) ((const __attribute__((address_space(1))) void*)(p))
#define GLDS16(src, dst) __builtin_amdgcn_global_load_lds(AS1(src), AS3(dst), 16, 0, 0)

#define BAR() asm volatile("s_barrier" ::: "memory")
#define VMC(n) asm volatile("s_waitcnt vmcnt(" #n ")" ::: "memory")

__device__ __forceinline__ u16 f2bf(float f) {
  union { float f; unsigned u; } c; c.f = f;
  unsigned u = c.u;
  return (u16)((u + 0x7FFFu + ((u >> 16) & 1u)) >> 16);
}

// ---- prep: all fp32->bf16 conversions + counts zeroing in ONE kernel ----
__global__ __launch_bounds__(256) void prep_kernel(
    const float4* __restrict__ x, const float4* __restrict__ wg,
    const float4* __restrict__ wu, const float4* __restrict__ wd,
    u16* __restrict__ x_bf, u16* __restrict__ wg_bf,
    u16* __restrict__ wu_bf, u16* __restrict__ wd_bf,
    int* __restrict__ counts)
{
  if (blockIdx.x == 0 && threadIdx.x < NEXP) counts[threadIdx.x] = 0;
  const int NX4 = T_TOK * H_DIM / 4;
  const int NW4 = NEXP * I_DIM * H_DIM / 4;
  const int total = NX4 + 3 * NW4;
  int i = blockIdx.x * blockDim.x + threadIdx.x;
  int s = gridDim.x * blockDim.x;
  for (; i < total; i += s) {
    const float4* src; u16* dst; int k;
    if (i < NX4) { src = x; dst = x_bf; k = i; }
    else {
      int r = i - NX4;
      if (r < NW4) { src = wg; dst = wg_bf; k = r; }
      else if (r < 2 * NW4) { src = wu; dst = wu_bf; k = r - NW4; }
      else { src = wd; dst = wd_bf; k = r - 2 * NW4; }
    }
    float4 v = src[k];
    ushort4 o;
    o.x = f2bf(v.x); o.y = f2bf(v.y); o.z = f2bf(v.z); o.w = f2bf(v.w);
    *(ushort4*)(dst + (size_t)k * 4) = o;
  }
}

// One block per token; 8 waves, wave e computes logit_e in fp64.
__global__ __launch_bounds__(512) void router_kernel(
    const float* __restrict__ x, const float* __restrict__ rw,
    float* __restrict__ probs, int* __restrict__ tok, float* __restrict__ wgt,
    int* __restrict__ counts, int4* __restrict__ ass)
{
  int t = blockIdx.x;
  int w = threadIdx.x >> 6, lane = threadIdx.x & 63;
  const float* xr = x + (size_t)t * H_DIM;
  const float* wr = rw + (size_t)w * H_DIM;
  double acc = 0.0;
  #pragma unroll
  for (int j = 0; j < H_DIM / 64; ++j) {
    int h = lane + 64 * j;
    acc += (double)xr[h] * (double)wr[h];
  }
  #pragma unroll
  for (int off = 32; off > 0; off >>= 1) acc += __shfl_down(acc, off);
  __shared__ double logits[NEXP];
  if (lane == 0) logits[w] = acc;
  __syncthreads();
  if (threadIdx.x == 0) {
    int i1 = 0;
    #pragma unroll
    for (int e = 1; e < NEXP; ++e) if (logits[e] > logits[i1]) i1 = e;
    int i2 = (i1 == 0) ? 1 : 0;
    #pragma unroll
    for (int e = 0; e < NEXP; ++e) {
      if (e == i1) continue;
      if (logits[e] > logits[i2]) i2 = e;
    }
    double l1 = logits[i1], l2 = logits[i2];
    float w1 = (float)(1.0 / (1.0 + exp(l2 - l1)));
    float w2 = 1.0f - w1;
    double m = l1, s = 0.0, p[NEXP];
    #pragma unroll
    for (int e = 0; e < NEXP; ++e) { p[e] = exp(logits[e] - m); s += p[e]; }
    #pragma unroll
    for (int e = 0; e < NEXP; ++e) probs[(size_t)t * NEXP + e] = (float)(p[e] / s);
    int p1 = atomicAdd(&counts[i1], 1);
    tok[i1 * T_TOK + p1] = t; wgt[i1 * T_TOK + p1] = w1;
    int p2 = atomicAdd(&counts[i2], 1);
    tok[i2 * T_TOK + p2] = t; wgt[i2 * T_TOK + p2] = w2;
    ass[t] = make_int4(i1, p1, i2, p2);
  }
}

// ---------------- shared 8-phase 256x256 BK=64 machinery ----------------
// LDS per buf: A 32KB @0, B 32KB @32768; 2 bufs (stride 65536) = 128KB.
// Swizzle: LDS byte (row,c) holds source col-byte c ^ ((row&7)<<4).
// Staging per tile: A x4 chunks at ph0 (VMC(4)), B x4 chunks at ph1.
// Cover: A = 4 phases, B = 3 phases; one vmcnt per K-tile.

#define DS_A(bb, qm) { \
  _Pragma("unroll") for (int ms = 0; ms < 4; ++ms) { \
  _Pragma("unroll") for (int ks = 0; ks < 2; ++ks) \
    af[ms][ks] = *(const bf16x8*)(lds + (bb) + aoff + ((qm)*64 + ms*16)*128 + ((ks<<6) ^ k0b)); } }

#define DS_B(bb, qn) { \
  _Pragma("unroll") for (int js = 0; js < 2; ++js) { \
  _Pragma("unroll") for (int ks = 0; ks < 2; ++ks) \
    bfr[js][ks] = *(const bf16x8*)(lds + (bb) + boff + ((qn)*128 + js*64)*128 + ((ks<<6) ^ k0b)); } }

#define MM(qm, qn) { \
  __builtin_amdgcn_s_setprio(1); \
  _Pragma("unroll") for (int ms = 0; ms < 4; ++ms) { \
  _Pragma("unroll") for (int js = 0; js < 2; ++js) { \
  _Pragma("unroll") for (int ks = 0; ks < 2; ++ks) \
    acc[(qm)*4+ms][(qn)*2+js] = __builtin_amdgcn_mfma_f32_16x16x32_bf16( \
        af[ms][ks], bfr[js][ks], acc[(qm)*4+ms][(qn)*2+js], 0, 0, 0); } } \
  __builtin_amdgcn_s_setprio(0); }

#define STGA(db) { \
  GLDS16(pA[0], lds + (db) + dst); GLDS16(pA[1], lds + (db) + 8192 + dst); \
  GLDS16(pA[2], lds + (db) + 16384 + dst); GLDS16(pA[3], lds + (db) + 24576 + dst); }
#define STGB(db) { \
  GLDS16(pB[0], lds + (db) + 32768 + dst); GLDS16(pB[1], lds + (db) + 40960 + dst); \
  GLDS16(pB[2], lds + (db) + 49152 + dst); GLDS16(pB[3], lds + (db) + 57344 + dst); }
#define ADV() { pA[0]+=64; pA[1]+=64; pA[2]+=64; pA[3]+=64; \
                pB[0]+=64; pB[1]+=64; pB[2]+=64; pB[3]+=64; }

#define MAIN_LOOP(NT) \
  STGA(0) STGB(0) ADV() \
  _Pragma("unroll 2") \
  for (int t = 0; t < (NT) - 1; ++t) { \
    unsigned cb = (unsigned)(t & 1) * 65536u; \
    unsigned sb = 65536u - cb; \
    STGA(sb) VMC(4); BAR(); \
    DS_A(cb, 0) DS_B(cb, 0) MM(0, 0) BAR(); \
    DS_A(cb, 1) STGB(sb) BAR(); \
    MM(1, 0) BAR(); \
    DS_B(cb, 1) BAR(); \
    MM(1, 1) BAR(); \
    DS_A(cb, 0) BAR(); \
    MM(0, 1) BAR(); \
    ADV() \
  } \
  { unsigned cb = (unsigned)(((NT) - 1) & 1) * 65536u; \
    VMC(0); BAR(); \
    DS_A(cb, 0) DS_B(cb, 0) MM(0, 0) \
    DS_A(cb, 1) MM(1, 0) \
    DS_B(cb, 1) MM(1, 1) \
    DS_A(cb, 0) MM(0, 1) }

// GEMM1: A = gathered tokens [256,K]; B virtual rows 0..127 = wg[hb..hb+128),
// 128..255 = wu[hb..hb+128)  -> in-register SwiGLU epilogue.
__global__ __launch_bounds__(512) void gemm1_kernel(
    const u16* __restrict__ x_bf, const u16* __restrict__ wg_bf,
    const u16* __restrict__ wu_bf, u16* __restrict__ h_bf,
    const int* __restrict__ tok, const int* __restrict__ counts)
{
  // flat 8192 blocks; lid = mbi + 32*hbi + 1024*e.  XCD swizzle: each XCD
  // gets 4 consecutive mbi of the same (hbi,e) weight panel (bijective).
  int f = blockIdx.x;
  int xcd = f & 7, slot = f >> 3;          // slot 0..1023
  int lid = (slot >> 2) * 32 + xcd * 4 + (slot & 3);
  int mb = (lid & 31) * 256;
  int hb = ((lid >> 5) & 31) * 128;
  int e = lid >> 10;

  int cnt = counts[e];
  if (mb >= cnt) return;
  int ofs = 0;
  #pragma unroll
  for (int k = 0; k < NEXP; ++k) ofs += (k < e) ? counts[k] : 0;

  int tid = threadIdx.x;
  __shared__ __align__(16) unsigned char lds[131072];

  int rloc = tid >> 3;
  int cbyte = (tid & 7) * 16;
  int cp = cbyte ^ ((rloc & 7) << 4);
  unsigned dst = (unsigned)tid * 16;

  const u16* pA[4];
  #pragma unroll
  for (int i = 0; i < 4; ++i) {
    int r = i * 64 + rloc;
    int tk = tok[e * T_TOK + min(mb + r, cnt - 1)];
    pA[i] = x_bf + (size_t)tk * H_DIM + (cp >> 1);
  }
  const u16* pB[4];
  #pragma unroll
  for (int i = 0; i < 2; ++i) {
    int r = i * 64 + rloc;
    pB[i]     = wg_bf + (size_t)e * I_DIM * H_DIM + (size_t)(hb + r) * H_DIM + (cp >> 1);
    pB[i + 2] = wu_bf + (size_t)e * I_DIM * H_DIM + (size_t)(hb + r) * H_DIM + (cp >> 1);
  }

  int wave = tid >> 6, lane = tid & 63;
  int wm = wave >> 2, wn = wave & 3;
  int lr = lane & 15;
  int k0b = ((lane >> 4) * 16) ^ ((lr & 7) << 4);
  unsigned aoff = (unsigned)(wm * 128 + lr) * 128;
  unsigned boff = 32768u + (unsigned)(wn * 16 + lr) * 128;

  f32x4 acc[8][4] = {};
  bf16x8 af[4][2], bfr[2][2];

  MAIN_LOOP(H_DIM / 64)

  // epilogue: in-register SwiGLU (gate acc[.][j], up acc[.][j+2], same h-col)
  int rr = (lane >> 4) * 4;
  #pragma unroll
  for (int mf = 0; mf < 8; ++mf) {
    #pragma unroll
    for (int r = 0; r < 4; ++r) {
      int row = mb + wm * 128 + mf * 16 + rr + r;
      if (row < cnt) {
        size_t base = (size_t)(ofs + row) * I_DIM + hb + wn * 16 + lr;
        #pragma unroll
        for (int j = 0; j < 2; ++j) {
          float gg = acc[mf][j][r];
          float uu = acc[mf][j + 2][r];
          float sg = gg / (1.f + __expf(-gg));
          h_bf[base + j * 64] = f2bf(sg * uu);
        }
      }
    }
  }
}

// GEMM2: y = h @ wd[e]^T (256x256 tile, K=4096), weighted store to y_buf.
__global__ __launch_bounds__(512) void gemm2_kernel(
    const u16* __restrict__ h_bf, const u16* __restrict__ wd_bf,
    float* __restrict__ y_buf, const float* __restrict__ wgt,
    const int* __restrict__ counts)
{
  // flat 1024 blocks; XCD swizzle keeps the 4 nb-blocks sharing an A-panel
  // (same e,mb) on one XCD.  lid = nb + 4*mb + 128*e
  int f = blockIdx.x;
  int xcd = f & 7, slot = f >> 3;
  int g = (slot >> 2) * 8 + xcd;
  int lid = g * 4 + (slot & 3);
  int nb = (lid & 3) * 256;
  int mb = ((lid >> 2) & 31) * 256;
  int e = lid >> 7;

  int cnt = counts[e];
  if (mb >= cnt) return;
  int ofs = 0;
  #pragma unroll
  for (int k = 0; k < NEXP; ++k) ofs += (k < e) ? counts[k] : 0;

  int tid = threadIdx.x;
  __shared__ __align__(16) unsigned char lds[131072];

  int rloc = tid >> 3;
  int cbyte = (tid & 7) * 16;
  int cp = cbyte ^ ((rloc & 7) << 4);
  unsigned dst = (unsigned)tid * 16;

  const u16* pA[4];
  #pragma unroll
  for (int i = 0; i < 4; ++i) {
    int r = i * 64 + rloc;
    int rowi = ofs + min(mb + r, cnt - 1);
    pA[i] = h_bf + (size_t)rowi * I_DIM + (cp >> 1);
  }
  const u16* pB[4];
  #pragma unroll
  for (int i = 0; i < 4; ++i) {
    int r = i * 64 + rloc;
    pB[i] = wd_bf + (size_t)e * H_DIM * I_DIM + (size_t)(nb + r) * I_DIM + (cp >> 1);
  }

  int wave = tid >> 6, lane = tid & 63;
  int wm = wave >> 2, wn = wave & 3;
  int lr = lane & 15;
  int k0b = ((lane >> 4) * 16) ^ ((lr & 7) << 4);
  unsigned aoff = (unsigned)(wm * 128 + lr) * 128;
  unsigned boff = 32768u + (unsigned)(wn * 16 + lr) * 128;

  f32x4 acc[8][4] = {};
  bf16x8 af[4][2], bfr[2][2];

  MAIN_LOOP(I_DIM / 64)

  int rr = (lane >> 4) * 4;
  #pragma unroll
  for (int mf = 0; mf < 8; ++mf) {
    #pragma unroll
    for (int r = 0; r < 4; ++r) {
      int pos = mb + wm * 128 + mf * 16 + rr + r;
      if (pos < cnt) {
        float wt = wgt[e * T_TOK + pos];
        size_t base = (size_t)(ofs + pos) * H_DIM + nb + wn * 16 + lr;
        #pragma unroll
        for (int q = 0; q < 2; ++q) {
          #pragma unroll
          for (int j = 0; j < 2; ++j)
            y_buf[base + q * 128 + j * 64] = wt * acc[mf][q * 2 + j][r];
        }
      }
    }
  }
}

// out[t] = y_buf[row(e1,p1)] + y_buf[row(e2,p2)]; last block computes aux loss.
__global__ __launch_bounds__(256) void combine_kernel(
    const float* __restrict__ y_buf, const int4* __restrict__ ass,
    const int* __restrict__ counts, float* __restrict__ out,
    const float* __restrict__ probs)
{
  if (blockIdx.x >= T_TOK) {
    __shared__ double part[256];
    int tid = threadIdx.x;
    int e = tid & 7;
    double s = 0.0;
    for (int t = tid >> 3; t < T_TOK; t += 32) s += probs[(size_t)t * NEXP + e];
    part[tid] = s;
    __syncthreads();
    if (tid < 8) {
      double u = 0.0;
      for (int i = tid; i < 256; i += 8) u += part[i];
      part[tid] = u;
    }
    __syncthreads();
    if (tid == 0) {
      double tot = 0.0;
      for (int k = 0; k < 8; ++k) tot += part[k];
      double aux = 0.0;
      for (int k = 0; k < 8; ++k) {
        double d = part[k] / tot - 0.125;
        aux += d * d;
      }
      out[(size_t)T_TOK * H_DIM] = (float)(0.01 * aux / 8.0);
    }
    return;
  }
  int off[NEXP];
  {
    int s = 0;
    #pragma unroll
    for (int k = 0; k < NEXP; ++k) { off[k] = s; s += counts[k]; }
  }
  int t = blockIdx.x;
  int4 a = ass[t];
  int h4 = threadIdx.x * 4;
  size_t p1 = (size_t)(off[a.x] + a.y) * H_DIM + h4;
  size_t p2 = (size_t)(off[a.z] + a.w) * H_DIM + h4;
  float4 v1 = *(const float4*)(y_buf + p1);
  float4 v2 = *(const float4*)(y_buf + p2);
  float4 o;
  o.x = v1.x + v2.x; o.y = v1.y + v2.y; o.z = v1.z + v2.z; o.w = v1.w + v2.w;
  *(float4*)(out + (size_t)t * H_DIM + h4) = o;
}

extern "C" void kernel_launch(void* const* d_in, const int* in_sizes, int n_in,
                              void* d_out, int out_size, void* d_ws, size_t ws_size,
                              hipStream_t stream) {
  const float* x  = (const float*)d_in[0];
  const float* rw = (const float*)d_in[1];
  const float* wg = (const float*)d_in[2];
  const float* wu = (const float*)d_in[3];
  const float* wd = (const float*)d_in[4];
  float* out = (float*)d_out;

  char* ws = (char*)d_ws;
  const size_t SZ_X  = (size_t)T_TOK * H_DIM * 2;            // 16 MB
  const size_t SZ_W  = (size_t)NEXP * I_DIM * H_DIM * 2;     // 64 MB each
  const size_t SZ_H  = (size_t)(2 * T_TOK + 256) * I_DIM * 2;
  u16* x_bf  = (u16*)(ws);
  u16* wg_bf = (u16*)(ws + SZ_X);
  u16* wu_bf = (u16*)(ws + SZ_X + SZ_W);
  u16* wd_bf = (u16*)(ws + SZ_X + 2 * SZ_W);
  u16* h_bf  = (u16*)(ws + SZ_X + 3 * SZ_W);
  // y_buf (f32, 2*T_TOK x H = 67 MB) aliases wg_bf+wu_bf (dead after gemm1)
  float* y_buf = (float*)(ws + SZ_X);
  char* tail = ws + SZ_X + 3 * SZ_W + SZ_H;
  float* probs = (float*)tail;
  int*   tok   = (int*)(tail + 262144);
  float* wgt   = (float*)(tail + 2 * 262144);
  int*   counts= (int*)(tail + 3 * 262144);
  int4*  ass   = (int4*)(tail + 3 * 262144 + 128);

  hipLaunchKernelGGL(prep_kernel, dim3(4096), dim3(256), 0, stream,
                     (const float4*)x, (const float4*)wg, (const float4*)wu,
                     (const float4*)wd, x_bf, wg_bf, wu_bf, wd_bf, counts);
  hipLaunchKernelGGL(router_kernel, dim3(T_TOK), dim3(512), 0, stream,
                     x, rw, probs, tok, wgt, counts, ass);
  hipLaunchKernelGGL(gemm1_kernel, dim3(8192), dim3(512), 0, stream,
                     x_bf, wg_bf, wu_bf, h_bf, tok, counts);
  hipLaunchKernelGGL(gemm2_kernel, dim3(1024), dim3(512), 0, stream,
                     h_bf, wd_bf, y_buf, wgt, counts);
  hipLaunchKernelGGL(combine_kernel, dim3(T_TOK + 1), dim3(256), 0, stream,
                     y_buf, ass, counts, out, probs);
}

// Round 6
// 972.075 us; speedup vs baseline: 1.6953x; 1.6953x over previous
//
#include <hip/hip_runtime.h>
#include <hip/hip_bf16.h>

#define T_TOK 8192
#define H_DIM 1024
#define I_DIM 4096
#define NEXP 8

typedef __bf16 bf16x8 __attribute__((ext_vector_type(8)));
typedef float f32x4 __attribute__((ext_vector_type(4)));
typedef unsigned short u16;

#define AS3(p) ((__attribute__((address_space(3))) void*)(p))
#define AS1(p) ((const __attribute__((address_space(1))) void*)(p))
#define GLDS16(src, dst) __builtin_amdgcn_global_load_lds(AS1(src), AS3(dst), 16, 0, 0)

#define BAR() asm volatile("s_barrier" ::: "memory")
#define VMC(n) asm volatile("s_waitcnt vmcnt(" #n ")" ::: "memory")

__device__ __forceinline__ u16 f2bf(float f) {
  union { float f; unsigned u; } c; c.f = f;
  unsigned u = c.u;
  return (u16)((u + 0x7FFFu + ((u >> 16) & 1u)) >> 16);
}

// ---- prep: all fp32->bf16 conversions + counts zeroing in ONE kernel ----
__global__ __launch_bounds__(256) void prep_kernel(
    const float4* __restrict__ x, const float4* __restrict__ wg,
    const float4* __restrict__ wu, const float4* __restrict__ wd,
    u16* __restrict__ x_bf, u16* __restrict__ wg_bf,
    u16* __restrict__ wu_bf, u16* __restrict__ wd_bf,
    int* __restrict__ counts)
{
  if (blockIdx.x == 0 && threadIdx.x < NEXP) counts[threadIdx.x] = 0;
  const int NX4 = T_TOK * H_DIM / 4;
  const int NW4 = NEXP * I_DIM * H_DIM / 4;
  const int total = NX4 + 3 * NW4;
  int i = blockIdx.x * blockDim.x + threadIdx.x;
  int s = gridDim.x * blockDim.x;
  for (; i < total; i += s) {
    const float4* src; u16* dst; int k;
    if (i < NX4) { src = x; dst = x_bf; k = i; }
    else {
      int r = i - NX4;
      if (r < NW4) { src = wg; dst = wg_bf; k = r; }
      else if (r < 2 * NW4) { src = wu; dst = wu_bf; k = r - NW4; }
      else { src = wd; dst = wd_bf; k = r - 2 * NW4; }
    }
    float4 v = src[k];
    ushort4 o;
    o.x = f2bf(v.x); o.y = f2bf(v.y); o.z = f2bf(v.z); o.w = f2bf(v.w);
    *(ushort4*)(dst + (size_t)k * 4) = o;
  }
}

// One block per token; 8 waves, wave e computes logit_e in fp64.
__global__ __launch_bounds__(512) void router_kernel(
    const float* __restrict__ x, const float* __restrict__ rw,
    float* __restrict__ probs, int* __restrict__ tok, float* __restrict__ wgt,
    int* __restrict__ counts, int4* __restrict__ ass)
{
  int t = blockIdx.x;
  int w = threadIdx.x >> 6, lane = threadIdx.x & 63;
  const float* xr = x + (size_t)t * H_DIM;
  const float* wr = rw + (size_t)w * H_DIM;
  double acc = 0.0;
  #pragma unroll
  for (int j = 0; j < H_DIM / 64; ++j) {
    int h = lane + 64 * j;
    acc += (double)xr[h] * (double)wr[h];
  }
  #pragma unroll
  for (int off = 32; off > 0; off >>= 1) acc += __shfl_down(acc, off);
  __shared__ double logits[NEXP];
  if (lane == 0) logits[w] = acc;
  __syncthreads();
  if (threadIdx.x == 0) {
    int i1 = 0;
    #pragma unroll
    for (int e = 1; e < NEXP; ++e) if (logits[e] > logits[i1]) i1 = e;
    int i2 = (i1 == 0) ? 1 : 0;
    #pragma unroll
    for (int e = 0; e < NEXP; ++e) {
      if (e == i1) continue;
      if (logits[e] > logits[i2]) i2 = e;
    }
    double l1 = logits[i1], l2 = logits[i2];
    float w1 = (float)(1.0 / (1.0 + exp(l2 - l1)));
    float w2 = 1.0f - w1;
    double m = l1, s = 0.0, p[NEXP];
    #pragma unroll
    for (int e = 0; e < NEXP; ++e) { p[e] = exp(logits[e] - m); s += p[e]; }
    #pragma unroll
    for (int e = 0; e < NEXP; ++e) probs[(size_t)t * NEXP + e] = (float)(p[e] / s);
    int p1 = atomicAdd(&counts[i1], 1);
    tok[i1 * T_TOK + p1] = t; wgt[i1 * T_TOK + p1] = w1;
    int p2 = atomicAdd(&counts[i2], 1);
    tok[i2 * T_TOK + p2] = t; wgt[i2 * T_TOK + p2] = w2;
    ass[t] = make_int4(i1, p1, i2, p2);
  }
}

// ---------------- shared 8-phase 256x256 BK=64 machinery ----------------
// LDS per buf: A 32KB @0, B 32KB @32768; 2 bufs (stride 65536) = 128KB.
// Swizzle: LDS byte (row,c) holds source col-byte c ^ ((row&7)<<4).
// Staging per tile: A x4 chunks at ph0 (VMC(4)), B x4 chunks at ph1.

#define DS_A(bb, qm) { \
  _Pragma("unroll") for (int ms = 0; ms < 4; ++ms) { \
  _Pragma("unroll") for (int ks = 0; ks < 2; ++ks) \
    af[ms][ks] = *(const bf16x8*)(lds + (bb) + aoff + ((qm)*64 + ms*16)*128 + ((ks<<6) ^ k0b)); } }

#define DS_B(bb, qn) { \
  _Pragma("unroll") for (int js = 0; js < 2; ++js) { \
  _Pragma("unroll") for (int ks = 0; ks < 2; ++ks) \
    bfr[js][ks] = *(const bf16x8*)(lds + (bb) + boff + ((qn)*128 + js*64)*128 + ((ks<<6) ^ k0b)); } }

#define MM(qm, qn) { \
  __builtin_amdgcn_s_setprio(1); \
  _Pragma("unroll") for (int ms = 0; ms < 4; ++ms) { \
  _Pragma("unroll") for (int js = 0; js < 2; ++js) { \
  _Pragma("unroll") for (int ks = 0; ks < 2; ++ks) \
    acc[(qm)*4+ms][(qn)*2+js] = __builtin_amdgcn_mfma_f32_16x16x32_bf16( \
        af[ms][ks], bfr[js][ks], acc[(qm)*4+ms][(qn)*2+js], 0, 0, 0); } } \
  __builtin_amdgcn_s_setprio(0); }

#define STGA(db) { \
  GLDS16(pA[0], lds + (db) + dst); GLDS16(pA[1], lds + (db) + 8192 + dst); \
  GLDS16(pA[2], lds + (db) + 16384 + dst); GLDS16(pA[3], lds + (db) + 24576 + dst); }
#define STGB(db) { \
  GLDS16(pB[0], lds + (db) + 32768 + dst); GLDS16(pB[1], lds + (db) + 40960 + dst); \
  GLDS16(pB[2], lds + (db) + 49152 + dst); GLDS16(pB[3], lds + (db) + 57344 + dst); }
#define ADV() { pA[0]+=64; pA[1]+=64; pA[2]+=64; pA[3]+=64; \
                pB[0]+=64; pB[1]+=64; pB[2]+=64; pB[3]+=64; }

#define MAIN_LOOP(NT) \
  STGA(0) STGB(0) ADV() \
  _Pragma("unroll 2") \
  for (int t = 0; t < (NT) - 1; ++t) { \
    unsigned cb = (unsigned)(t & 1) * 65536u; \
    unsigned sb = 65536u - cb; \
    STGA(sb) VMC(4); BAR(); \
    DS_A(cb, 0) DS_B(cb, 0) MM(0, 0) BAR(); \
    DS_A(cb, 1) STGB(sb) BAR(); \
    MM(1, 0) BAR(); \
    DS_B(cb, 1) BAR(); \
    MM(1, 1) BAR(); \
    DS_A(cb, 0) BAR(); \
    MM(0, 1) BAR(); \
    ADV() \
  } \
  { unsigned cb = (unsigned)(((NT) - 1) & 1) * 65536u; \
    VMC(0); BAR(); \
    DS_A(cb, 0) DS_B(cb, 0) MM(0, 0) \
    DS_A(cb, 1) MM(1, 0) \
    DS_B(cb, 1) MM(1, 1) \
    DS_A(cb, 0) MM(0, 1) }

// GEMM1: A = gathered tokens [256,K]; B virtual rows 0..127 = wg[hb..hb+128),
// 128..255 = wu[hb..hb+128)  -> in-register SwiGLU epilogue.
__global__ __launch_bounds__(512) void gemm1_kernel(
    const u16* __restrict__ x_bf, const u16* __restrict__ wg_bf,
    const u16* __restrict__ wu_bf, u16* __restrict__ h_bf,
    const int* __restrict__ tok, const int* __restrict__ counts)
{
  // 8192 blocks.  xcd = f&7 (HW round-robin).  mbi (ragged dim) lives in
  // slot&31 -> uniform per XCD; panel P = (slot>>5)*8 + xcd covers all
  // experts evenly.  Consecutive same-XCD blocks share one weight panel.
  int f = blockIdx.x;
  int xcd = f & 7, slot = f >> 3;          // slot 0..1023
  int mbi = slot & 31;
  int P = (slot >> 5) * 8 + xcd;           // 0..255
  int mb = mbi * 256;
  int hb = (P & 31) * 128;
  int e = P >> 5;

  int cnt = counts[e];
  if (mb >= cnt) return;
  int ofs = 0;
  #pragma unroll
  for (int k = 0; k < NEXP; ++k) ofs += (k < e) ? counts[k] : 0;

  int tid = threadIdx.x;
  __shared__ __align__(16) unsigned char lds[131072];

  int rloc = tid >> 3;
  int cbyte = (tid & 7) * 16;
  int cp = cbyte ^ ((rloc & 7) << 4);
  unsigned dst = (unsigned)tid * 16;

  const u16* pA[4];
  #pragma unroll
  for (int i = 0; i < 4; ++i) {
    int r = i * 64 + rloc;
    int tk = tok[e * T_TOK + min(mb + r, cnt - 1)];
    pA[i] = x_bf + (size_t)tk * H_DIM + (cp >> 1);
  }
  const u16* pB[4];
  #pragma unroll
  for (int i = 0; i < 2; ++i) {
    int r = i * 64 + rloc;
    pB[i]     = wg_bf + (size_t)e * I_DIM * H_DIM + (size_t)(hb + r) * H_DIM + (cp >> 1);
    pB[i + 2] = wu_bf + (size_t)e * I_DIM * H_DIM + (size_t)(hb + r) * H_DIM + (cp >> 1);
  }

  int wave = tid >> 6, lane = tid & 63;
  int wm = wave >> 2, wn = wave & 3;
  int lr = lane & 15;
  int k0b = ((lane >> 4) * 16) ^ ((lr & 7) << 4);
  unsigned aoff = (unsigned)(wm * 128 + lr) * 128;
  unsigned boff = 32768u + (unsigned)(wn * 16 + lr) * 128;

  f32x4 acc[8][4] = {};
  bf16x8 af[4][2], bfr[2][2];

  MAIN_LOOP(H_DIM / 64)

  // epilogue: in-register SwiGLU (gate acc[.][j], up acc[.][j+2], same h-col)
  int rr = (lane >> 4) * 4;
  #pragma unroll
  for (int mf = 0; mf < 8; ++mf) {
    #pragma unroll
    for (int r = 0; r < 4; ++r) {
      int row = mb + wm * 128 + mf * 16 + rr + r;
      if (row < cnt) {
        size_t base = (size_t)(ofs + row) * I_DIM + hb + wn * 16 + lr;
        #pragma unroll
        for (int j = 0; j < 2; ++j) {
          float gg = acc[mf][j][r];
          float uu = acc[mf][j + 2][r];
          float sg = gg / (1.f + __expf(-gg));
          h_bf[base + j * 64] = f2bf(sg * uu);
        }
      }
    }
  }
}

// GEMM2: y = h @ wd[e]^T (256x256 tile, K=4096), weighted store to y_buf.
__global__ __launch_bounds__(512) void gemm2_kernel(
    const u16* __restrict__ h_bf, const u16* __restrict__ wd_bf,
    float* __restrict__ y_buf, const float* __restrict__ wgt,
    const int* __restrict__ counts)
{
  // 1024 blocks.  mbi in slot&31 (uniform per XCD); panel P = (slot>>5)*8+xcd
  // -> (e = P>>2, nb = P&3): each wd-panel (2MB, L2-fit) owned by one XCD.
  int f = blockIdx.x;
  int xcd = f & 7, slot = f >> 3;          // slot 0..127
  int mbi = slot & 31;
  int P = (slot >> 5) * 8 + xcd;           // 0..31
  int mb = mbi * 256;
  int nb = (P & 3) * 256;
  int e = P >> 2;

  int cnt = counts[e];
  if (mb >= cnt) return;
  int ofs = 0;
  #pragma unroll
  for (int k = 0; k < NEXP; ++k) ofs += (k < e) ? counts[k] : 0;

  int tid = threadIdx.x;
  __shared__ __align__(16) unsigned char lds[131072];

  int rloc = tid >> 3;
  int cbyte = (tid & 7) * 16;
  int cp = cbyte ^ ((rloc & 7) << 4);
  unsigned dst = (unsigned)tid * 16;

  const u16* pA[4];
  #pragma unroll
  for (int i = 0; i < 4; ++i) {
    int r = i * 64 + rloc;
    int rowi = ofs + min(mb + r, cnt - 1);
    pA[i] = h_bf + (size_t)rowi * I_DIM + (cp >> 1);
  }
  const u16* pB[4];
  #pragma unroll
  for (int i = 0; i < 4; ++i) {
    int r = i * 64 + rloc;
    pB[i] = wd_bf + (size_t)e * H_DIM * I_DIM + (size_t)(nb + r) * I_DIM + (cp >> 1);
  }

  int wave = tid >> 6, lane = tid & 63;
  int wm = wave >> 2, wn = wave & 3;
  int lr = lane & 15;
  int k0b = ((lane >> 4) * 16) ^ ((lr & 7) << 4);
  unsigned aoff = (unsigned)(wm * 128 + lr) * 128;
  unsigned boff = 32768u + (unsigned)(wn * 16 + lr) * 128;

  f32x4 acc[8][4] = {};
  bf16x8 af[4][2], bfr[2][2];

  MAIN_LOOP(I_DIM / 64)

  int rr = (lane >> 4) * 4;
  #pragma unroll
  for (int mf = 0; mf < 8; ++mf) {
    #pragma unroll
    for (int r = 0; r < 4; ++r) {
      int pos = mb + wm * 128 + mf * 16 + rr + r;
      if (pos < cnt) {
        float wt = wgt[e * T_TOK + pos];
        size_t base = (size_t)(ofs + pos) * H_DIM + nb + wn * 16 + lr;
        #pragma unroll
        for (int q = 0; q < 2; ++q) {
          #pragma unroll
          for (int j = 0; j < 2; ++j)
            y_buf[base + q * 128 + j * 64] = wt * acc[mf][q * 2 + j][r];
        }
      }
    }
  }
}

// out[t] = y_buf[row(e1,p1)] + y_buf[row(e2,p2)]; last block computes aux loss.
__global__ __launch_bounds__(256) void combine_kernel(
    const float* __restrict__ y_buf, const int4* __restrict__ ass,
    const int* __restrict__ counts, float* __restrict__ out,
    const float* __restrict__ probs)
{
  if (blockIdx.x >= T_TOK) {
    __shared__ double part[256];
    int tid = threadIdx.x;
    int e = tid & 7;
    double s = 0.0;
    for (int t = tid >> 3; t < T_TOK; t += 32) s += probs[(size_t)t * NEXP + e];
    part[tid] = s;
    __syncthreads();
    if (tid < 8) {
      double u = 0.0;
      for (int i = tid; i < 256; i += 8) u += part[i];
      part[tid] = u;
    }
    __syncthreads();
    if (tid == 0) {
      double tot = 0.0;
      for (int k = 0; k < 8; ++k) tot += part[k];
      double aux = 0.0;
      for (int k = 0; k < 8; ++k) {
        double d = part[k] / tot - 0.125;
        aux += d * d;
      }
      out[(size_t)T_TOK * H_DIM] = (float)(0.01 * aux / 8.0);
    }
    return;
  }
  int off[NEXP];
  {
    int s = 0;
    #pragma unroll
    for (int k = 0; k < NEXP; ++k) { off[k] = s; s += counts[k]; }
  }
  int t = blockIdx.x;
  int4 a = ass[t];
  int h4 = threadIdx.x * 4;
  size_t p1 = (size_t)(off[a.x] + a.y) * H_DIM + h4;
  size_t p2 = (size_t)(off[a.z] + a.w) * H_DIM + h4;
  float4 v1 = *(const float4*)(y_buf + p1);
  float4 v2 = *(const float4*)(y_buf + p2);
  float4 o;
  o.x = v1.x + v2.x; o.y = v1.y + v2.y; o.z = v1.z + v2.z; o.w = v1.w + v2.w;
  *(float4*)(out + (size_t)t * H_DIM + h4) = o;
}

extern "C" void kernel_launch(void* const* d_in, const int* in_sizes, int n_in,
                              void* d_out, int out_size, void* d_ws, size_t ws_size,
                              hipStream_t stream) {
  const float* x  = (const float*)d_in[0];
  const float* rw = (const float*)d_in[1];
  const float* wg = (const float*)d_in[2];
  const float* wu = (const float*)d_in[3];
  const float* wd = (const float*)d_in[4];
  float* out = (float*)d_out;

  char* ws = (char*)d_ws;
  const size_t SZ_X  = (size_t)T_TOK * H_DIM * 2;            // 16 MB
  const size_t SZ_W  = (size_t)NEXP * I_DIM * H_DIM * 2;     // 64 MB each
  const size_t SZ_H  = (size_t)(2 * T_TOK + 256) * I_DIM * 2;
  u16* x_bf  = (u16*)(ws);
  u16* wg_bf = (u16*)(ws + SZ_X);
  u16* wu_bf = (u16*)(ws + SZ_X + SZ_W);
  u16* wd_bf = (u16*)(ws + SZ_X + 2 * SZ_W);
  u16* h_bf  = (u16*)(ws + SZ_X + 3 * SZ_W);
  // y_buf (f32, 2*T_TOK x H = 67 MB) aliases wg_bf+wu_bf (dead after gemm1)
  float* y_buf = (float*)(ws + SZ_X);
  char* tail = ws + SZ_X + 3 * SZ_W + SZ_H;
  float* probs = (float*)tail;
  int*   tok   = (int*)(tail + 262144);
  float* wgt   = (float*)(tail + 2 * 262144);
  int*   counts= (int*)(tail + 3 * 262144);
  int4*  ass   = (int4*)(tail + 3 * 262144 + 128);

  hipLaunchKernelGGL(prep_kernel, dim3(4096), dim3(256), 0, stream,
                     (const float4*)x, (const float4*)wg, (const float4*)wu,
                     (const float4*)wd, x_bf, wg_bf, wu_bf, wd_bf, counts);
  hipLaunchKernelGGL(router_kernel, dim3(T_TOK), dim3(512), 0, stream,
                     x, rw, probs, tok, wgt, counts, ass);
  hipLaunchKernelGGL(gemm1_kernel, dim3(8192), dim3(512), 0, stream,
                     x_bf, wg_bf, wu_bf, h_bf, tok, counts);
  hipLaunchKernelGGL(gemm2_kernel, dim3(1024), dim3(512), 0, stream,
                     h_bf, wd_bf, y_buf, wgt, counts);
  hipLaunchKernelGGL(combine_kernel, dim3(T_TOK + 1), dim3(256), 0, stream,
                     y_buf, ass, counts, out, probs);
}

// Round 11
// 947.345 us; speedup vs baseline: 1.7396x; 1.0261x over previous
//
#include <hip/hip_runtime.h>
#include <hip/hip_bf16.h>

#define T_TOK 8192
#define H_DIM 1024
#define I_DIM 4096
#define NEXP 8

typedef __bf16 bf16x8 __attribute__((ext_vector_type(8)));
typedef float f32x4 __attribute__((ext_vector_type(4)));
typedef unsigned short u16;

#define AS3(p) ((__attribute__((address_space(3))) void*)(p))
#define AS1(p) ((const __attribute__((address_space(1))) void*)(p))
#define GLDS16(src, dst) __builtin_amdgcn_global_load_lds(AS1(src), AS3(dst), 16, 0, 0)

#define BAR() asm volatile("s_barrier" ::: "memory")
#define VMC(n) asm volatile("s_waitcnt vmcnt(" #n ")" ::: "memory")

__device__ __forceinline__ u16 f2bf(float f) {
  union { float f; unsigned u; } c; c.f = f;
  unsigned u = c.u;
  return (u16)((u + 0x7FFFu + ((u >> 16) & 1u)) >> 16);
}

// ---- prep: all fp32->bf16 conversions + counts zeroing in ONE kernel ----
__global__ __launch_bounds__(256) void prep_kernel(
    const float4* __restrict__ x, const float4* __restrict__ wg,
    const float4* __restrict__ wu, const float4* __restrict__ wd,
    u16* __restrict__ x_bf, u16* __restrict__ wg_bf,
    u16* __restrict__ wu_bf, u16* __restrict__ wd_bf,
    int* __restrict__ counts)
{
  if (blockIdx.x == 0 && threadIdx.x < NEXP) counts[threadIdx.x] = 0;
  const int NX4 = T_TOK * H_DIM / 4;
  const int NW4 = NEXP * I_DIM * H_DIM / 4;
  const int total = NX4 + 3 * NW4;
  int i = blockIdx.x * blockDim.x + threadIdx.x;
  int s = gridDim.x * blockDim.x;
  for (; i < total; i += s) {
    const float4* src; u16* dst; int k;
    if (i < NX4) { src = x; dst = x_bf; k = i; }
    else {
      int r = i - NX4;
      if (r < NW4) { src = wg; dst = wg_bf; k = r; }
      else if (r < 2 * NW4) { src = wu; dst = wu_bf; k = r - NW4; }
      else { src = wd; dst = wd_bf; k = r - 2 * NW4; }
    }
    float4 v = src[k];
    ushort4 o;
    o.x = f2bf(v.x); o.y = f2bf(v.y); o.z = f2bf(v.z); o.w = f2bf(v.w);
    *(ushort4*)(dst + (size_t)k * 4) = o;
  }
}

// One block per token; 8 waves, wave e computes logit_e in fp64.
__global__ __launch_bounds__(512) void router_kernel(
    const float* __restrict__ x, const float* __restrict__ rw,
    float* __restrict__ probs, int* __restrict__ tok, float* __restrict__ wgt,
    int* __restrict__ counts, int4* __restrict__ ass)
{
  int t = blockIdx.x;
  int w = threadIdx.x >> 6, lane = threadIdx.x & 63;
  const float* xr = x + (size_t)t * H_DIM;
  const float* wr = rw + (size_t)w * H_DIM;
  double acc = 0.0;
  #pragma unroll
  for (int j = 0; j < H_DIM / 64; ++j) {
    int h = lane + 64 * j;
    acc += (double)xr[h] * (double)wr[h];
  }
  #pragma unroll
  for (int off = 32; off > 0; off >>= 1) acc += __shfl_down(acc, off);
  __shared__ double logits[NEXP];
  if (lane == 0) logits[w] = acc;
  __syncthreads();
  if (threadIdx.x == 0) {
    int i1 = 0;
    #pragma unroll
    for (int e = 1; e < NEXP; ++e) if (logits[e] > logits[i1]) i1 = e;
    int i2 = (i1 == 0) ? 1 : 0;
    #pragma unroll
    for (int e = 0; e < NEXP; ++e) {
      if (e == i1) continue;
      if (logits[e] > logits[i2]) i2 = e;
    }
    double l1 = logits[i1], l2 = logits[i2];
    float w1 = (float)(1.0 / (1.0 + exp(l2 - l1)));
    float w2 = 1.0f - w1;
    double m = l1, s = 0.0, p[NEXP];
    #pragma unroll
    for (int e = 0; e < NEXP; ++e) { p[e] = exp(logits[e] - m); s += p[e]; }
    #pragma unroll
    for (int e = 0; e < NEXP; ++e) probs[(size_t)t * NEXP + e] = (float)(p[e] / s);
    int p1 = atomicAdd(&counts[i1], 1);
    tok[i1 * T_TOK + p1] = t; wgt[i1 * T_TOK + p1] = w1;
    int p2 = atomicAdd(&counts[i2], 1);
    tok[i2 * T_TOK + p2] = t; wgt[i2 * T_TOK + p2] = w2;
    ass[t] = make_int4(i1, p1, i2, p2);
  }
}

// ---------------- shared 8-phase 256x256 BK=64 machinery ----------------
// LDS per buf: A 32KB @0, B 32KB @32768; 2 bufs (stride 65536) = 128KB.
// Swizzle: LDS byte (row,c) holds source col-byte c ^ ((row&7)<<4).
// Staging per tile: A x4 chunks at ph0 (VMC(4)), B x4 chunks at ph1.

#define DS_A(bb, qm) { \
  _Pragma("unroll") for (int ms = 0; ms < 4; ++ms) { \
  _Pragma("unroll") for (int ks = 0; ks < 2; ++ks) \
    af[ms][ks] = *(const bf16x8*)(lds + (bb) + aoff + ((qm)*64 + ms*16)*128 + ((ks<<6) ^ k0b)); } }

#define DS_B(bb, qn) { \
  _Pragma("unroll") for (int js = 0; js < 2; ++js) { \
  _Pragma("unroll") for (int ks = 0; ks < 2; ++ks) \
    bfr[js][ks] = *(const bf16x8*)(lds + (bb) + boff + ((qn)*128 + js*64)*128 + ((ks<<6) ^ k0b)); } }

#define MM(qm, qn) { \
  __builtin_amdgcn_s_setprio(1); \
  _Pragma("unroll") for (int ms = 0; ms < 4; ++ms) { \
  _Pragma("unroll") for (int js = 0; js < 2; ++js) { \
  _Pragma("unroll") for (int ks = 0; ks < 2; ++ks) \
    acc[(qm)*4+ms][(qn)*2+js] = __builtin_amdgcn_mfma_f32_16x16x32_bf16( \
        af[ms][ks], bfr[js][ks], acc[(qm)*4+ms][(qn)*2+js], 0, 0, 0); } } \
  __builtin_amdgcn_s_setprio(0); }

#define STGA(db) { \
  GLDS16(pA[0], lds + (db) + dst); GLDS16(pA[1], lds + (db) + 8192 + dst); \
  GLDS16(pA[2], lds + (db) + 16384 + dst); GLDS16(pA[3], lds + (db) + 24576 + dst); }
#define STGB(db) { \
  GLDS16(pB[0], lds + (db) + 32768 + dst); GLDS16(pB[1], lds + (db) + 40960 + dst); \
  GLDS16(pB[2], lds + (db) + 49152 + dst); GLDS16(pB[3], lds + (db) + 57344 + dst); }
#define ADV() { pA[0]+=64; pA[1]+=64; pA[2]+=64; pA[3]+=64; \
                pB[0]+=64; pB[1]+=64; pB[2]+=64; pB[3]+=64; }

#define MAIN_LOOP(NT) \
  STGA(0) STGB(0) ADV() \
  _Pragma("unroll 2") \
  for (int t = 0; t < (NT) - 1; ++t) { \
    unsigned cb = (unsigned)(t & 1) * 65536u; \
    unsigned sb = 65536u - cb; \
    STGA(sb) VMC(4); BAR(); \
    DS_A(cb, 0) DS_B(cb, 0) MM(0, 0) BAR(); \
    DS_A(cb, 1) STGB(sb) BAR(); \
    MM(1, 0) BAR(); \
    DS_B(cb, 1) BAR(); \
    MM(1, 1) BAR(); \
    DS_A(cb, 0) BAR(); \
    MM(0, 1) BAR(); \
    ADV() \
  } \
  { unsigned cb = (unsigned)(((NT) - 1) & 1) * 65536u; \
    VMC(0); BAR(); \
    DS_A(cb, 0) DS_B(cb, 0) MM(0, 0) \
    DS_A(cb, 1) MM(1, 0) \
    DS_B(cb, 1) MM(1, 1) \
    DS_A(cb, 0) MM(0, 1) }

// GEMM1: A = gathered tokens [256,K]; B virtual rows 0..127 = wg[hb..hb+128),
// 128..255 = wu[hb..hb+128)  -> in-register SwiGLU epilogue.
// Natural 3D grid (32, 32, 8): x=hb panel, y=mb, z=expert.
__global__ __launch_bounds__(512) void gemm1_kernel(
    const u16* __restrict__ x_bf, const u16* __restrict__ wg_bf,
    const u16* __restrict__ wu_bf, u16* __restrict__ h_bf,
    const int* __restrict__ tok, const int* __restrict__ counts)
{
  int e = blockIdx.z;
  int mb = blockIdx.y * 256;
  int hb = blockIdx.x * 128;

  int cnt = counts[e];
  if (mb >= cnt) return;
  int ofs = 0;
  #pragma unroll
  for (int k = 0; k < NEXP; ++k) ofs += (k < e) ? counts[k] : 0;

  int tid = threadIdx.x;
  __shared__ __align__(16) unsigned char lds[131072];

  int rloc = tid >> 3;
  int cbyte = (tid & 7) * 16;
  int cp = cbyte ^ ((rloc & 7) << 4);
  unsigned dst = (unsigned)tid * 16;

  const u16* pA[4];
  #pragma unroll
  for (int i = 0; i < 4; ++i) {
    int r = i * 64 + rloc;
    int tk = tok[e * T_TOK + min(mb + r, cnt - 1)];
    pA[i] = x_bf + (size_t)tk * H_DIM + (cp >> 1);
  }
  const u16* pB[4];
  #pragma unroll
  for (int i = 0; i < 2; ++i) {
    int r = i * 64 + rloc;
    pB[i]     = wg_bf + (size_t)e * I_DIM * H_DIM + (size_t)(hb + r) * H_DIM + (cp >> 1);
    pB[i + 2] = wu_bf + (size_t)e * I_DIM * H_DIM + (size_t)(hb + r) * H_DIM + (cp >> 1);
  }

  int wave = tid >> 6, lane = tid & 63;
  int wm = wave >> 2, wn = wave & 3;
  int lr = lane & 15;
  int k0b = ((lane >> 4) * 16) ^ ((lr & 7) << 4);
  unsigned aoff = (unsigned)(wm * 128 + lr) * 128;
  unsigned boff = 32768u + (unsigned)(wn * 16 + lr) * 128;

  f32x4 acc[8][4] = {};
  bf16x8 af[4][2], bfr[2][2];

  MAIN_LOOP(H_DIM / 64)

  // epilogue: in-register SwiGLU (gate acc[.][j], up acc[.][j+2], same h-col)
  int rr = (lane >> 4) * 4;
  #pragma unroll
  for (int mf = 0; mf < 8; ++mf) {
    #pragma unroll
    for (int r = 0; r < 4; ++r) {
      int row = mb + wm * 128 + mf * 16 + rr + r;
      if (row < cnt) {
        size_t base = (size_t)(ofs + row) * I_DIM + hb + wn * 16 + lr;
        #pragma unroll
        for (int j = 0; j < 2; ++j) {
          float gg = acc[mf][j][r];
          float uu = acc[mf][j + 2][r];
          float sg = gg / (1.f + __expf(-gg));
          h_bf[base + j * 64] = f2bf(sg * uu);
        }
      }
    }
  }
}

// GEMM2: y = h @ wd[e]^T (256x256 tile, K=4096), weighted store to y_buf.
// Natural 3D grid (4, 32, 8): x=nb, y=mb, z=expert.
__global__ __launch_bounds__(512) void gemm2_kernel(
    const u16* __restrict__ h_bf, const u16* __restrict__ wd_bf,
    float* __restrict__ y_buf, const float* __restrict__ wgt,
    const int* __restrict__ counts)
{
  int e = blockIdx.z;
  int mb = blockIdx.y * 256;
  int nb = blockIdx.x * 256;

  int cnt = counts[e];
  if (mb >= cnt) return;
  int ofs = 0;
  #pragma unroll
  for (int k = 0; k < NEXP; ++k) ofs += (k < e) ? counts[k] : 0;

  int tid = threadIdx.x;
  __shared__ __align__(16) unsigned char lds[131072];

  int rloc = tid >> 3;
  int cbyte = (tid & 7) * 16;
  int cp = cbyte ^ ((rloc & 7) << 4);
  unsigned dst = (unsigned)tid * 16;

  const u16* pA[4];
  #pragma unroll
  for (int i = 0; i < 4; ++i) {
    int r = i * 64 + rloc;
    int rowi = ofs + min(mb + r, cnt - 1);
    pA[i] = h_bf + (size_t)rowi * I_DIM + (cp >> 1);
  }
  const u16* pB[4];
  #pragma unroll
  for (int i = 0; i < 4; ++i) {
    int r = i * 64 + rloc;
    pB[i] = wd_bf + (size_t)e * H_DIM * I_DIM + (size_t)(nb + r) * I_DIM + (cp >> 1);
  }

  int wave = tid >> 6, lane = tid & 63;
  int wm = wave >> 2, wn = wave & 3;
  int lr = lane & 15;
  int k0b = ((lane >> 4) * 16) ^ ((lr & 7) << 4);
  unsigned aoff = (unsigned)(wm * 128 + lr) * 128;
  unsigned boff = 32768u + (unsigned)(wn * 16 + lr) * 128;

  f32x4 acc[8][4] = {};
  bf16x8 af[4][2], bfr[2][2];

  MAIN_LOOP(I_DIM / 64)

  int rr = (lane >> 4) * 4;
  #pragma unroll
  for (int mf = 0; mf < 8; ++mf) {
    #pragma unroll
    for (int r = 0; r < 4; ++r) {
      int pos = mb + wm * 128 + mf * 16 + rr + r;
      if (pos < cnt) {
        float wt = wgt[e * T_TOK + pos];
        size_t base = (size_t)(ofs + pos) * H_DIM + nb + wn * 16 + lr;
        #pragma unroll
        for (int q = 0; q < 2; ++q) {
          #pragma unroll
          for (int j = 0; j < 2; ++j)
            y_buf[base + q * 128 + j * 64] = wt * acc[mf][q * 2 + j][r];
        }
      }
    }
  }
}

// out[t] = y_buf[row(e1,p1)] + y_buf[row(e2,p2)]; last block computes aux loss.
__global__ __launch_bounds__(256) void combine_kernel(
    const float* __restrict__ y_buf, const int4* __restrict__ ass,
    const int* __restrict__ counts, float* __restrict__ out,
    const float* __restrict__ probs)
{
  if (blockIdx.x >= T_TOK) {
    __shared__ double part[256];
    int tid = threadIdx.x;
    int e = tid & 7;
    double s = 0.0;
    for (int t = tid >> 3; t < T_TOK; t += 32) s += probs[(size_t)t * NEXP + e];
    part[tid] = s;
    __syncthreads();
    if (tid < 8) {
      double u = 0.0;
      for (int i = tid; i < 256; i += 8) u += part[i];
      part[tid] = u;
    }
    __syncthreads();
    if (tid == 0) {
      double tot = 0.0;
      for (int k = 0; k < 8; ++k) tot += part[k];
      double aux = 0.0;
      for (int k = 0; k < 8; ++k) {
        double d = part[k] / tot - 0.125;
        aux += d * d;
      }
      out[(size_t)T_TOK * H_DIM] = (float)(0.01 * aux / 8.0);
    }
    return;
  }
  int off[NEXP];
  {
    int s = 0;
    #pragma unroll
    for (int k = 0; k < NEXP; ++k) { off[k] = s; s += counts[k]; }
  }
  int t = blockIdx.x;
  int4 a = ass[t];
  int h4 = threadIdx.x * 4;
  size_t p1 = (size_t)(off[a.x] + a.y) * H_DIM + h4;
  size_t p2 = (size_t)(off[a.z] + a.w) * H_DIM + h4;
  float4 v1 = *(const float4*)(y_buf + p1);
  float4 v2 = *(const float4*)(y_buf + p2);
  float4 o;
  o.x = v1.x + v2.x; o.y = v1.y + v2.y; o.z = v1.z + v2.z; o.w = v1.w + v2.w;
  *(float4*)(out + (size_t)t * H_DIM + h4) = o;
}

extern "C" void kernel_launch(void* const* d_in, const int* in_sizes, int n_in,
                              void* d_out, int out_size, void* d_ws, size_t ws_size,
                              hipStream_t stream) {
  const float* x  = (const float*)d_in[0];
  const float* rw = (const float*)d_in[1];
  const float* wg = (const float*)d_in[2];
  const float* wu = (const float*)d_in[3];
  const float* wd = (const float*)d_in[4];
  float* out = (float*)d_out;

  char* ws = (char*)d_ws;
  const size_t SZ_X  = (size_t)T_TOK * H_DIM * 2;            // 16 MB
  const size_t SZ_W  = (size_t)NEXP * I_DIM * H_DIM * 2;     // 64 MB each
  const size_t SZ_H  = (size_t)(2 * T_TOK + 256) * I_DIM * 2;
  u16* x_bf  = (u16*)(ws);
  u16* wg_bf = (u16*)(ws + SZ_X);
  u16* wu_bf = (u16*)(ws + SZ_X + SZ_W);
  u16* wd_bf = (u16*)(ws + SZ_X + 2 * SZ_W);
  u16* h_bf  = (u16*)(ws + SZ_X + 3 * SZ_W);
  // y_buf (f32, 16384 x 1024 = 64 MiB) aliases wg_bf+wu_bf (dead after gemm1)
  float* y_buf = (float*)(ws + SZ_X);
  char* tail = ws + SZ_X + 3 * SZ_W + SZ_H;
  float* probs = (float*)tail;
  int*   tok   = (int*)(tail + 262144);
  float* wgt   = (float*)(tail + 2 * 262144);
  int*   counts= (int*)(tail + 3 * 262144);
  int4*  ass   = (int4*)(tail + 3 * 262144 + 128);

  hipLaunchKernelGGL(prep_kernel, dim3(4096), dim3(256), 0, stream,
                     (const float4*)x, (const float4*)wg, (const float4*)wu,
                     (const float4*)wd, x_bf, wg_bf, wu_bf, wd_bf, counts);
  hipLaunchKernelGGL(router_kernel, dim3(T_TOK), dim3(512), 0, stream,
                     x, rw, probs, tok, wgt, counts, ass);
  hipLaunchKernelGGL(gemm1_kernel, dim3(32, 32, NEXP), dim3(512), 0, stream,
                     x_bf, wg_bf, wu_bf, h_bf, tok, counts);
  hipLaunchKernelGGL(gemm2_kernel, dim3(4, 32, NEXP), dim3(512), 0, stream,
                     h_bf, wd_bf, y_buf, wgt, counts);
  hipLaunchKernelGGL(combine_kernel, dim3(T_TOK + 1), dim3(256), 0, stream,
                     y_buf, ass, counts, out, probs);
}